// Round 3
// baseline (681.689 us; speedup 1.0000x reference)
//
#include <hip/hip_runtime.h>
#include <stdint.h>

#define COLS 16384
#define VPT 16             // vf4 per thread: 16 x 4 = 64 floats; whole row register-resident
#define POOLCAP 320        // E[pool] ~ 20 with the tighter 256-minima threshold
typedef unsigned long long u64;
typedef float vf4 __attribute__((ext_vector_type(4)));

// Order-preserving float32 -> uint32 mapping (ascending float == ascending uint).
__device__ __forceinline__ uint32_t f2key(float x) {
  uint32_t u = __float_as_uint(x);
  u ^= (uint32_t)((int32_t)u >> 31) | 0x80000000u;
  return u;
}

// One BLOCK per row (was: one wave per row). The block sweeps its 64 KB row
// contiguously -- 4 KB per load instruction across 256 threads -- replicating
// the access shape of the harness fill that measures 6.4 TB/s, instead of
// 4096 independent 64KB-strided wave-private streams (measured ~1.6 TB/s,
// invariant under prefetch depth and start-phase).
__global__ __launch_bounds__(256, 4) void KNNC_20272245637217_kernel(
    const float* __restrict__ dist,
    const int* __restrict__ labels,
    int* __restrict__ out) {
  const int tid  = threadIdx.x;
  const int wave = tid >> 6;
  const int lane = tid & 63;
  const int row  = blockIdx.x;

  __shared__ u64   poolK[POOLCAP];   // (sortable value bits << 32) | column idx
  __shared__ float tmin[64];         // each wave's 16 smallest thread-minima
  __shared__ float Tsh;
  __shared__ int   cnt;
  if (tid == 0) cnt = 0;
  __syncthreads();

  const vf4* __restrict__ rp = (const vf4*)(dist + (size_t)row * COLS);

  // ---- Load the whole row once, block-contiguous; stays in registers ----
  vf4 V[VPT];
  #pragma unroll
  for (int i = 0; i < VPT; ++i) V[i] = rp[tid + 256 * i];

  // ---- Per-thread min over its 64 elements ----
  float m = __builtin_inff();
  #pragma unroll
  for (int i = 0; i < VPT; ++i)
    m = fminf(m, fminf(fminf(V[i].x, V[i].y), fminf(V[i].z, V[i].w)));

  // ---- Wave-level bitonic sort of the 64 thread-minima (lane L = L-th smallest) ----
  float v = m;
  #pragma unroll
  for (int k = 2; k <= 64; k <<= 1) {
    #pragma unroll
    for (int j = k >> 1; j >= 1; j >>= 1) {
      float o = __shfl_xor(v, j);
      bool keepMin = (((lane & j) == 0) == ((lane & k) == 0));
      v = keepMin ? fminf(v, o) : fmaxf(v, o);
    }
  }
  // Each wave contributes its 16 smallest; the global 16 smallest of the 256
  // thread-minima are contained in this 64-candidate union.
  if (lane < 16) tmin[wave * 16 + lane] = v;
  __syncthreads();

  // ---- Wave 0: T = 16th smallest of the 256 thread-minima ----
  // T >= row's true 16th smallest: the 16 smallest thread-minima are 16
  // DISTINCT row elements (disjoint per-thread element sets), all <= T.
  if (wave == 0) {
    float w = tmin[lane];
    #pragma unroll
    for (int k = 2; k <= 64; k <<= 1) {
      #pragma unroll
      for (int j = k >> 1; j >= 1; j >>= 1) {
        float o = __shfl_xor(w, j);
        bool keepMin = (((lane & j) == 0) == ((lane & k) == 0));
        w = keepMin ? fminf(w, o) : fmaxf(w, o);
      }
    }
    if (lane == 15) Tsh = w;
  }
  __syncthreads();
  const float T = Tsh;

  // ---- Scan register-resident row; push candidates <= T into the block pool ----
#define PUSH(x, c) { if ((x) <= T) { \
    int _s = atomicAdd(&cnt, 1); \
    if (_s < POOLCAP) poolK[_s] = (((u64)f2key(x)) << 32) | (u64)(uint32_t)(c); } }

  #pragma unroll
  for (int i = 0; i < VPT; ++i) {
    vf4 w = V[i];
    float mn = fminf(fminf(w.x, w.y), fminf(w.z, w.w));
    if (mn <= T) {
      int col = (tid + 256 * i) * 4;
      PUSH(w.x, col) PUSH(w.y, col + 1) PUSH(w.z, col + 2) PUSH(w.w, col + 3)
    }
  }
  __syncthreads();

  // ---- Wave 0: exact top-16 extraction + majority vote ----
  if (wave == 0) {
    int C = cnt;
    if (C > POOLCAP) C = POOLCAP;   // defensive; C >= 16 by T's construction

    u64 key[5];
    #pragma unroll
    for (int t = 0; t < 5; ++t) {
      int p = lane + 64 * t;
      key[t] = (p < C) ? poolK[p] : ~0ULL;
    }

    u64 myWin = ~0ULL;
    for (int r = 0; r < 16; ++r) {
      u64 k = key[0];
      #pragma unroll
      for (int t = 1; t < 5; ++t) k = (key[t] < k) ? key[t] : k;
      #pragma unroll
      for (int off = 32; off >= 1; off >>= 1) {
        u64 o = __shfl_xor(k, off);
        k = (o < k) ? o : k;
      }
      if (lane == r) myWin = k;           // lane r records the r-th smallest
      #pragma unroll
      for (int t = 0; t < 5; ++t)
        if (key[t] == k) key[t] = ~0ULL;  // keys unique (idx in low bits)
    }

    // u64 keys reproduce top_k's (value, index) tie-break exactly.
    int myLabel = 0;
    if (lane < 16) myLabel = labels[(uint32_t)myWin];  // low 32 bits = column idx

    int c = 0;
    #pragma unroll
    for (int s = 0; s < 16; ++s) {
      int ls = __shfl(myLabel, s);
      c += (ls == myLabel) ? 1 : 0;
    }
    // maximize count, then minimize label (argmax-first semantics)
    int vkey = (lane < 16) ? ((c << 7) | (127 - myLabel)) : 0;
    #pragma unroll
    for (int off = 32; off >= 1; off >>= 1) {
      int o = __shfl_xor(vkey, off);
      vkey = (o > vkey) ? o : vkey;
    }
    if (lane == 0) out[row] = 127 - (vkey & 127);
  }
}

extern "C" void kernel_launch(void* const* d_in, const int* in_sizes, int n_in,
                              void* d_out, int out_size, void* d_ws, size_t ws_size,
                              hipStream_t stream) {
  const float* dist   = (const float*)d_in[0];
  const int*   labels = (const int*)d_in[1];
  int*         out    = (int*)d_out;
  const int rows = out_size;          // 8192
  KNNC_20272245637217_kernel<<<rows, 256, 0, stream>>>(dist, labels, out);
}